// Round 3
// baseline (8936.835 us; speedup 1.0000x reference)
//
#include <hip/hip_runtime.h>
#include <stdint.h>
#include <stddef.h>

typedef __attribute__((ext_vector_type(8))) short short8;
typedef __attribute__((ext_vector_type(4))) short short4_t;
typedef __attribute__((ext_vector_type(8))) unsigned short ushort8_t;
typedef __attribute__((ext_vector_type(4))) unsigned short ushort4_t;
typedef __attribute__((ext_vector_type(4))) float f32x4;
typedef __attribute__((ext_vector_type(4))) unsigned uint4_t;

// workspace layout (bytes) — identical footprint to round 1 (validated)
#define XG_BYTES  (134217728ull)          // xg: [1024 t][4 g][1024 n][16 b] bf16
#define HS_BYTES  (33587200ull)           // hs: [1025 t][16 b][1024 k] bf16
#define PAD_OFF   (XG_BYTES + HS_BYTES)   // (unused 32KB, keeps round-1 offsets)
#define WT_OFF    (PAD_OFF + 32768ull)    // Wt: [5][1024 n][1024 k] bf16 (4 x-gates + post)

#define SENT 0x7FC07FC0u                  // bf16 NaN pair — h is finite, never equals this

__device__ __forceinline__ unsigned short f2b(float f){
  unsigned u = __builtin_bit_cast(unsigned, f);
  u += 0x7fffu + ((u >> 16) & 1u);
  return (unsigned short)(u >> 16);
}
__device__ __forceinline__ float b2f(unsigned short b){
  unsigned u = ((unsigned)b) << 16;
  return __builtin_bit_cast(float, u);
}
__device__ __forceinline__ float sigm(float x){ return 1.0f / (1.0f + __expf(-x)); }
__device__ __forceinline__ float tanh_(float x){ return 2.0f / (1.0f + __expf(-2.0f*x)) - 1.0f; }

// ---------------- weight transpose+convert: W[k][n] f32 -> Wt[n][k] bf16 ----
__global__ __launch_bounds__(256) void k_prep(
    const float* __restrict__ w0, const float* __restrict__ w1,
    const float* __restrict__ w2, const float* __restrict__ w3,
    const float* __restrict__ w4, unsigned short* __restrict__ wt)
{
  const int z = blockIdx.z;
  const float* W = (z==0)?w0:(z==1)?w1:(z==2)?w2:(z==3)?w3:w4;
  unsigned short* out = wt + (size_t)z*1024*1024;
  __shared__ float tile[64][65];
  const int k0 = blockIdx.x*64, n0 = blockIdx.y*64;
  const int tid = threadIdx.x;
  {
    const int kk = tid >> 2, nn0 = (tid & 3) * 16;
    const float* src = W + (size_t)(k0+kk)*1024 + n0 + nn0;
    #pragma unroll
    for (int j=0;j<16;j+=4){
      f32x4 v = *(const f32x4*)(src + j);
      tile[kk][nn0+j+0]=v[0]; tile[kk][nn0+j+1]=v[1];
      tile[kk][nn0+j+2]=v[2]; tile[kk][nn0+j+3]=v[3];
    }
  }
  __syncthreads();
  {
    const int nn = tid >> 2, kk0 = (tid & 3) * 16;
    ushort8_t a, b;
    #pragma unroll
    for (int j=0;j<8;++j){ a[j]=f2b(tile[kk0+j][nn]); b[j]=f2b(tile[kk0+8+j][nn]); }
    unsigned short* dst = out + (size_t)(n0+nn)*1024 + k0 + kk0;
    *(ushort8_t*)dst = a;
    *(ushort8_t*)(dst+8) = b;
  }
}

// ---------------- h0 -> hs[0] bf16 ------------------------------------------
__global__ void k_init(const float* __restrict__ h0, unsigned short* __restrict__ hs){
  const int i = blockIdx.x*256 + threadIdx.x;
  hs[i] = f2b(h0[i]);
}

// ---------------- sentinel-fill hs[1..1024] ---------------------------------
__global__ void k_fill(unsigned* __restrict__ hsw){
  const size_t i = (size_t)blockIdx.x*256 + threadIdx.x;   // 2,097,152 threads
  uint4_t v = (uint4_t){SENT, SENT, SENT, SENT};
  *(uint4_t*)(hsw + 8192 + i*4) = v;                       // slot1 starts at word 8192
}

// ---------------- x projections: xg[t][g][n][b] = x @ Wx + bx (bf16 out) ----
__global__ __launch_bounds__(256,2) void k_xproj(
    const float* __restrict__ xF, const float* __restrict__ xI,
    const float* __restrict__ xZ, const float* __restrict__ xO,
    const float* __restrict__ bF, const float* __restrict__ bI,
    const float* __restrict__ bZ, const float* __restrict__ bO,
    const unsigned short* __restrict__ Wt,   // [4][n][k] bf16
    unsigned short* __restrict__ xg)
{
  const int g  = blockIdx.z;
  const int tm = blockIdx.x, tn = blockIdx.y;
  const float* X  = (g==0)?xF:(g==1)?xI:(g==2)?xZ:xO;
  const float* Bp = (g==0)?bF:(g==1)?bI:(g==2)?bZ:bO;
  const unsigned short* Wg = Wt + (size_t)g*1024*1024;

  __shared__ unsigned short Asm[128*32];
  __shared__ unsigned short Bsm[128*32];

  const int tid  = threadIdx.x;
  const int lane = tid & 63, wv = tid >> 6;
  const int l15  = lane & 15, lg = lane >> 4;
  const int wy   = wv >> 1,  wx = wv & 1;

  const int rr = tid >> 1, kq = tid & 1;
  const int ar = tm*128 + rr;
  const int ab = ar & 15, as_ = ar >> 4;
  const float* aptr = X + ((size_t)ab*1024 + as_)*1024 + kq*16;
  const unsigned short* bp_ = Wg + (size_t)(tn*128 + rr)*1024 + kq*16;
  const int s0 = kq*2;
  unsigned short* aw0 = &Asm[rr*32 + (((s0  ) ^ (rr&3))<<3)];
  unsigned short* aw1 = &Asm[rr*32 + (((s0+1) ^ (rr&3))<<3)];
  unsigned short* bw0 = &Bsm[rr*32 + (((s0  ) ^ (rr&3))<<3)];
  unsigned short* bw1 = &Bsm[rr*32 + (((s0+1) ^ (rr&3))<<3)];

  f32x4 acc[4][4];
  #pragma unroll
  for (int m=0;m<4;++m)
    #pragma unroll
    for (int q=0;q<4;++q) acc[m][q] = (f32x4){0.f,0.f,0.f,0.f};

  for (int k0=0; k0<1024; k0+=32){
    const float* ap = aptr + k0;
    f32x4 v0 = *(const f32x4*)(ap + 0);
    f32x4 v1 = *(const f32x4*)(ap + 4);
    f32x4 v2 = *(const f32x4*)(ap + 8);
    f32x4 v3 = *(const f32x4*)(ap + 12);
    ushort8_t pa, pb;
    #pragma unroll
    for (int j=0;j<4;++j){ pa[j]=f2b(v0[j]); pa[4+j]=f2b(v1[j]); pb[j]=f2b(v2[j]); pb[4+j]=f2b(v3[j]); }
    *(ushort8_t*)aw0 = pa;
    *(ushort8_t*)aw1 = pb;
    ushort8_t q0 = *(const ushort8_t*)(bp_ + k0);
    ushort8_t q1 = *(const ushort8_t*)(bp_ + k0 + 8);
    *(ushort8_t*)bw0 = q0;
    *(ushort8_t*)bw1 = q1;
    __syncthreads();

    short8 af[4], bf_[4];
    #pragma unroll
    for (int m=0;m<4;++m){
      int row = wy*64 + m*16 + l15;
      af[m] = *(const short8*)&Asm[row*32 + ((lg ^ (row&3))<<3)];
    }
    #pragma unroll
    for (int q=0;q<4;++q){
      int row = wx*64 + q*16 + l15;
      bf_[q] = *(const short8*)&Bsm[row*32 + ((lg ^ (row&3))<<3)];
    }
    #pragma unroll
    for (int m=0;m<4;++m)
      #pragma unroll
      for (int q=0;q<4;++q)
        acc[m][q] = __builtin_amdgcn_mfma_f32_16x16x32_bf16(af[m], bf_[q], acc[m][q], 0,0,0);
    __syncthreads();
  }

  #pragma unroll
  for (int m=0;m<4;++m){
    const int t = tm*8 + wy*4 + m;
    #pragma unroll
    for (int q=0;q<4;++q){
      const int n = tn*128 + wx*64 + q*16 + l15;
      const float bias = Bp[n];
      f32x4 v = acc[m][q];
      ushort4_t pk;
      #pragma unroll
      for (int r=0;r<4;++r) pk[r] = f2b(v[r] + bias);
      *(ushort4_t*)(xg + (size_t)((t*4+g)*1024 + n)*16 + lg*4) = pk;
    }
  }
}

// ---------------- persistent recurrence (fence-free atomic mailbox) ---------
// 64 WGs; WG wg owns output cols [wg*16,+16); wave wv holds K-slice [wv*256,+256)
// in 128 weight VGPRs. h exchanged as u32 bf16-pairs via relaxed agent atomics;
// word != SENT means ready. No fences, no flags, no L2 invalidates.
__global__ __launch_bounds__(256,1) void k_recur(
    const float* __restrict__ Wfh, const float* __restrict__ Wih,
    const float* __restrict__ Wzh, const float* __restrict__ Woh,
    const float* __restrict__ bfh, const float* __restrict__ bih,
    const float* __restrict__ bzh, const float* __restrict__ boh,
    const float* __restrict__ c0,
    const unsigned short* __restrict__ xg,
    unsigned short* __restrict__ hs,
    float* __restrict__ oc, float* __restrict__ oh)
{
  const int wg   = blockIdx.x;          // 0..63
  const int tid  = threadIdx.x;
  const int wv   = tid >> 6, lane = tid & 63;
  const int l15  = lane & 15, lg = lane >> 4;
  const int n    = wg*16 + l15;

  // register-resident recurrent weights: wave wv holds K slice [wv*256, +256)
  short8 wf[4][8];
  {
    const float* Wp[4] = {Wfh, Wih, Wzh, Woh};
    #pragma unroll
    for (int g=0; g<4; ++g){
      #pragma unroll
      for (int c=0; c<8; ++c){
        short8 v;
        #pragma unroll
        for (int i=0; i<8; ++i){
          int k = wv*256 + c*32 + lg*8 + i;
          v[i] = (short)f2b(Wp[g][(size_t)k*1024 + n]);
        }
        wf[g][c] = v;
      }
    }
  }
  float cst[4]; float bias[4];
  if (wv == 0){
    bias[0]=bfh[n]; bias[1]=bih[n]; bias[2]=bzh[n]; bias[3]=boh[n];
    #pragma unroll
    for (int r=0;r<4;++r) cst[r] = c0[(size_t)(lg*4+r)*1024 + n];
  }
  __shared__ f32x4 part[3][4][64];

  unsigned* hsw = (unsigned*)hs;
  // per-lane A-fragment word base: row l15, k-slice of this wave
  const unsigned wbase0 = (unsigned)(l15*512 + wv*128 + lg*4);

  for (int t=0; t<1024; ++t){
    // prefetch xg[t] (plain cached loads, no invalidates anywhere)
    short4_t xq[4];
    if (wv == 0){
      #pragma unroll
      for (int g=0; g<4; ++g)
        xq[g] = *(const short4_t*)(xg + (size_t)((t*4+g)*1024 + n)*16 + lg*4);
    }

    // poll-load this wave's A fragments: 32 u32 words, valid when != SENT
    unsigned* base = hsw + (size_t)t*8192;
    unsigned w[32];
    #pragma unroll
    for (int c=0;c<8;++c)
      #pragma unroll
      for (int j=0;j<4;++j)
        w[c*4+j] = __hip_atomic_load(base + wbase0 + c*16 + j,
                                     __ATOMIC_RELAXED, __HIP_MEMORY_SCOPE_AGENT);
    for (;;){
      bool ok = true;
      #pragma unroll
      for (int q=0;q<32;++q) ok &= (w[q] != SENT);
      if (__all(ok)) break;
      #pragma unroll
      for (int c=0;c<8;++c)
        #pragma unroll
        for (int j=0;j<4;++j)
          if (w[c*4+j] == SENT)
            w[c*4+j] = __hip_atomic_load(base + wbase0 + c*16 + j,
                                         __ATOMIC_RELAXED, __HIP_MEMORY_SCOPE_AGENT);
    }

    f32x4 acc[4];
    #pragma unroll
    for (int g=0;g<4;++g) acc[g] = (f32x4){0.f,0.f,0.f,0.f};
    #pragma unroll
    for (int c=0;c<8;++c){
      uint4_t qw = (uint4_t){w[c*4], w[c*4+1], w[c*4+2], w[c*4+3]};
      short8 a = __builtin_bit_cast(short8, qw);
      acc[0] = __builtin_amdgcn_mfma_f32_16x16x32_bf16(a, wf[0][c], acc[0], 0,0,0);
      acc[1] = __builtin_amdgcn_mfma_f32_16x16x32_bf16(a, wf[1][c], acc[1], 0,0,0);
      acc[2] = __builtin_amdgcn_mfma_f32_16x16x32_bf16(a, wf[2][c], acc[2], 0,0,0);
      acc[3] = __builtin_amdgcn_mfma_f32_16x16x32_bf16(a, wf[3][c], acc[3], 0,0,0);
    }
    if (wv > 0){
      #pragma unroll
      for (int g=0;g<4;++g) part[wv-1][g][lane] = acc[g];
    }
    __syncthreads();
    if (wv == 0){
      #pragma unroll
      for (int p=0;p<3;++p)
        #pragma unroll
        for (int g=0;g<4;++g) acc[g] += part[p][g][lane];
    }
    __syncthreads();   // 'part' free for next step's writers
    if (wv == 0){
      float hv[4];
      #pragma unroll
      for (int r=0;r<4;++r){
        float pf = acc[0][r] + b2f((unsigned short)xq[0][r]) + bias[0];
        float pi = acc[1][r] + b2f((unsigned short)xq[1][r]) + bias[1];
        float pz = acc[2][r] + b2f((unsigned short)xq[2][r]) + bias[2];
        float po = acc[3][r] + b2f((unsigned short)xq[3][r]) + bias[3];
        float fg = sigm(pf), ig = sigm(pi), zg = tanh_(pz), og = sigm(po);
        float cn = fg*cst[r] + ig*zg;
        cst[r] = cn;
        hv[r] = og * tanh_(cn);
      }
      // pack bf16 pairs across lane^1 (cols n even/odd), even lanes store u32
      #pragma unroll
      for (int r=0;r<4;++r){
        unsigned m  = (unsigned)f2b(hv[r]);
        unsigned nb = (unsigned)__shfl_xor(m, 1);
        if ((l15 & 1) == 0){
          unsigned word = m | (nb << 16);
          unsigned idx  = (unsigned)((t+1)*8192 + (lg*4+r)*512 + (n >> 1));
          __hip_atomic_store(hsw + idx, word, __ATOMIC_RELAXED, __HIP_MEMORY_SCOPE_AGENT);
        }
      }
      if (t == 1023){
        #pragma unroll
        for (int r=0;r<4;++r){
          oc[(size_t)(lg*4+r)*1024 + n] = cst[r];
          oh[(size_t)(lg*4+r)*1024 + n] = hv[r];
        }
      }
    }
  }
}

// ---------------- post projection: y[b][s][n] = hs[1..] @ Wpost + bpost -----
__global__ __launch_bounds__(256,2) void k_post(
    const unsigned short* __restrict__ hs,
    const unsigned short* __restrict__ Wt,   // post slice at +4M
    const float* __restrict__ bpost,
    float* __restrict__ y)
{
  const int tm = blockIdx.x, tn = blockIdx.y;
  __shared__ unsigned short Asm[128*32];
  __shared__ unsigned short Bsm[128*32];

  const int tid  = threadIdx.x;
  const int lane = tid & 63, wv = tid >> 6;
  const int l15  = lane & 15, lg = lane >> 4;
  const int wy   = wv >> 1,  wx = wv & 1;

  const int rr = tid >> 1, kq = tid & 1;
  const unsigned short* aptr = hs + 16384 + (size_t)(tm*128 + rr)*1024 + kq*16;
  const unsigned short* bp_  = Wt + (size_t)4*1024*1024 + (size_t)(tn*128 + rr)*1024 + kq*16;
  const int s0 = kq*2;
  unsigned short* aw0 = &Asm[rr*32 + (((s0  ) ^ (rr&3))<<3)];
  unsigned short* aw1 = &Asm[rr*32 + (((s0+1) ^ (rr&3))<<3)];
  unsigned short* bw0 = &Bsm[rr*32 + (((s0  ) ^ (rr&3))<<3)];
  unsigned short* bw1 = &Bsm[rr*32 + (((s0+1) ^ (rr&3))<<3)];

  f32x4 acc[4][4];
  #pragma unroll
  for (int m=0;m<4;++m)
    #pragma unroll
    for (int q=0;q<4;++q) acc[m][q] = (f32x4){0.f,0.f,0.f,0.f};

  for (int k0=0; k0<1024; k0+=32){
    ushort8_t a0 = *(const ushort8_t*)(aptr + k0);
    ushort8_t a1 = *(const ushort8_t*)(aptr + k0 + 8);
    *(ushort8_t*)aw0 = a0;
    *(ushort8_t*)aw1 = a1;
    ushort8_t q0 = *(const ushort8_t*)(bp_ + k0);
    ushort8_t q1 = *(const ushort8_t*)(bp_ + k0 + 8);
    *(ushort8_t*)bw0 = q0;
    *(ushort8_t*)bw1 = q1;
    __syncthreads();

    short8 af[4], bf_[4];
    #pragma unroll
    for (int m=0;m<4;++m){
      int row = wy*64 + m*16 + l15;
      af[m] = *(const short8*)&Asm[row*32 + ((lg ^ (row&3))<<3)];
    }
    #pragma unroll
    for (int q=0;q<4;++q){
      int row = wx*64 + q*16 + l15;
      bf_[q] = *(const short8*)&Bsm[row*32 + ((lg ^ (row&3))<<3)];
    }
    #pragma unroll
    for (int m=0;m<4;++m)
      #pragma unroll
      for (int q=0;q<4;++q)
        acc[m][q] = __builtin_amdgcn_mfma_f32_16x16x32_bf16(af[m], bf_[q], acc[m][q], 0,0,0);
    __syncthreads();
  }

  #pragma unroll
  for (int m=0;m<4;++m){
    const int s = tm*8 + wy*4 + m;
    #pragma unroll
    for (int q=0;q<4;++q){
      const int n = tn*128 + wx*64 + q*16 + l15;
      const float bias = bpost[n];
      f32x4 v = acc[m][q];
      #pragma unroll
      for (int r=0;r<4;++r){
        const int b = lg*4 + r;
        y[((size_t)b << 20) + ((size_t)s << 10) + n] = v[r] + bias;
      }
    }
  }
}

extern "C" void kernel_launch(void* const* d_in, const int* in_sizes, int n_in,
                              void* d_out, int out_size, void* d_ws, size_t ws_size,
                              hipStream_t stream)
{
  const float* f_in = (const float*)d_in[0];
  const float* i_in = (const float*)d_in[1];
  const float* z_in = (const float*)d_in[2];
  const float* o_in = (const float*)d_in[3];
  const float* c0   = (const float*)d_in[4];
  const float* h0   = (const float*)d_in[5];
  const float* W_Fx = (const float*)d_in[6];  const float* b_Fx = (const float*)d_in[7];
  const float* W_Ix = (const float*)d_in[8];  const float* b_Ix = (const float*)d_in[9];
  const float* W_Zx = (const float*)d_in[10]; const float* b_Zx = (const float*)d_in[11];
  const float* W_Ox = (const float*)d_in[12]; const float* b_Ox = (const float*)d_in[13];
  const float* W_Fh = (const float*)d_in[14]; const float* b_Fh = (const float*)d_in[15];
  const float* W_Ih = (const float*)d_in[16]; const float* b_Ih = (const float*)d_in[17];
  const float* W_Zh = (const float*)d_in[18]; const float* b_Zh = (const float*)d_in[19];
  const float* W_Oh = (const float*)d_in[20]; const float* b_Oh = (const float*)d_in[21];
  const float* W_post = (const float*)d_in[22]; const float* b_post = (const float*)d_in[23];

  char* ws = (char*)d_ws;
  unsigned short* xg    = (unsigned short*)(ws);
  unsigned short* hs    = (unsigned short*)(ws + XG_BYTES);
  unsigned short* wt    = (unsigned short*)(ws + WT_OFF);

  float* y  = (float*)d_out;
  float* oc = y + 16777216;   // 16*1024*1024
  float* oh = oc + 16384;

  k_prep<<<dim3(16,16,5), 256, 0, stream>>>(W_Fx, W_Ix, W_Zx, W_Ox, W_post, wt);
  k_init<<<64, 256, 0, stream>>>(h0, hs);
  k_fill<<<8192, 256, 0, stream>>>((unsigned*)hs);
  k_xproj<<<dim3(128,8,4), 256, 0, stream>>>(f_in, i_in, z_in, o_in,
                                             b_Fx, b_Ix, b_Zx, b_Ox, wt, xg);
  k_recur<<<64, 256, 0, stream>>>(W_Fh, W_Ih, W_Zh, W_Oh,
                                  b_Fh, b_Ih, b_Zh, b_Oh,
                                  c0, xg, hs, oc, oh);
  k_post<<<dim3(128,8), 256, 0, stream>>>(hs, wt, b_post, y);
}

// Round 4
// 4440.398 us; speedup vs baseline: 2.0126x; 2.0126x over previous
//
#include <hip/hip_runtime.h>
#include <stdint.h>
#include <stddef.h>

typedef __attribute__((ext_vector_type(8))) short short8;
typedef __attribute__((ext_vector_type(4))) short short4_t;
typedef __attribute__((ext_vector_type(8))) unsigned short ushort8_t;
typedef __attribute__((ext_vector_type(4))) unsigned short ushort4_t;
typedef __attribute__((ext_vector_type(4))) float f32x4;
typedef __attribute__((ext_vector_type(4))) unsigned uint4_t;

// workspace layout (bytes)
#define XG_BYTES  (134217728ull)          // xg: [1024 t][4 g][1024 n][16 b] bf16
#define HS_BYTES  (33587200ull)           // hs: [1025 t][16 b][1024 k] bf16
#define FLAGS_OFF (XG_BYTES + HS_BYTES)   // 64 flags, 128B apart (8 KB used)
#define WT_OFF    (FLAGS_OFF + 32768ull)  // Wt: [9][1024 n][1024 k] bf16
#define FSTRIDE   32                      // u32 stride between flags (128 B)

#define SENT 0x7FC07FC0u                  // bf16 NaN pair — h is finite, never equals this

__device__ __forceinline__ unsigned short f2b(float f){
  unsigned u = __builtin_bit_cast(unsigned, f);
  u += 0x7fffu + ((u >> 16) & 1u);
  return (unsigned short)(u >> 16);
}
__device__ __forceinline__ float b2f(unsigned short b){
  unsigned u = ((unsigned)b) << 16;
  return __builtin_bit_cast(float, u);
}
__device__ __forceinline__ float sigm(float x){ return 1.0f / (1.0f + __expf(-x)); }
__device__ __forceinline__ float tanh_(float x){ return 2.0f / (1.0f + __expf(-2.0f*x)) - 1.0f; }

// ---- coherence-point (MALL) primitives: sc0 sc1 = bypass L1 and L2 --------
__device__ __forceinline__ unsigned ld_u32_mall(const unsigned* p){
  unsigned v;
  asm volatile("global_load_dword %0, %1, off sc0 sc1\n\t"
               "s_waitcnt vmcnt(0)"
               : "=v"(v) : "v"(p) : "memory");
  return v;
}
__device__ __forceinline__ void ld_h8_mall(const unsigned short* p, short8* a){
  asm volatile(
    "global_load_dwordx4 %0, %8, off sc0 sc1\n\t"
    "global_load_dwordx4 %1, %8, off offset:64 sc0 sc1\n\t"
    "global_load_dwordx4 %2, %8, off offset:128 sc0 sc1\n\t"
    "global_load_dwordx4 %3, %8, off offset:192 sc0 sc1\n\t"
    "global_load_dwordx4 %4, %8, off offset:256 sc0 sc1\n\t"
    "global_load_dwordx4 %5, %8, off offset:320 sc0 sc1\n\t"
    "global_load_dwordx4 %6, %8, off offset:384 sc0 sc1\n\t"
    "global_load_dwordx4 %7, %8, off offset:448 sc0 sc1\n\t"
    "s_waitcnt vmcnt(0)"
    : "=&v"(a[0]), "=&v"(a[1]), "=&v"(a[2]), "=&v"(a[3]),
      "=&v"(a[4]), "=&v"(a[5]), "=&v"(a[6]), "=&v"(a[7])
    : "v"(p) : "memory");
}
// 4 u32 stores at row strides (2KB apart), then drain to coherence point
__device__ __forceinline__ void st_h4_mall(unsigned* p, unsigned w0, unsigned w1,
                                           unsigned w2, unsigned w3){
  asm volatile(
    "global_store_dword %0, %2, off sc0 sc1\n\t"
    "global_store_dword %0, %3, off offset:2048 sc0 sc1\n\t"
    "global_store_dword %1, %4, off sc0 sc1\n\t"
    "global_store_dword %1, %5, off offset:2048 sc0 sc1\n\t"
    :: "v"(p), "v"(p + 1024), "v"(w0), "v"(w1), "v"(w2), "v"(w3) : "memory");
}
__device__ __forceinline__ void st_flag_mall(unsigned* p, unsigned v){
  asm volatile("global_store_dword %0, %1, off sc0 sc1"
               :: "v"(p), "v"(v) : "memory");
}

// ---------------- weight transpose+convert: W[k][n] f32 -> Wt[n][k] bf16 ----
__global__ __launch_bounds__(256) void k_prep(
    const float* __restrict__ w0, const float* __restrict__ w1,
    const float* __restrict__ w2, const float* __restrict__ w3,
    const float* __restrict__ w4, const float* __restrict__ w5,
    const float* __restrict__ w6, const float* __restrict__ w7,
    const float* __restrict__ w8, unsigned short* __restrict__ wt)
{
  const int z = blockIdx.z;
  const float* W = (z==0)?w0:(z==1)?w1:(z==2)?w2:(z==3)?w3:(z==4)?w4:
                   (z==5)?w5:(z==6)?w6:(z==7)?w7:w8;
  unsigned short* out = wt + (size_t)z*1024*1024;
  __shared__ float tile[64][65];
  const int k0 = blockIdx.x*64, n0 = blockIdx.y*64;
  const int tid = threadIdx.x;
  {
    const int kk = tid >> 2, nn0 = (tid & 3) * 16;
    const float* src = W + (size_t)(k0+kk)*1024 + n0 + nn0;
    #pragma unroll
    for (int j=0;j<16;j+=4){
      f32x4 v = *(const f32x4*)(src + j);
      tile[kk][nn0+j+0]=v[0]; tile[kk][nn0+j+1]=v[1];
      tile[kk][nn0+j+2]=v[2]; tile[kk][nn0+j+3]=v[3];
    }
  }
  __syncthreads();
  {
    const int nn = tid >> 2, kk0 = (tid & 3) * 16;
    ushort8_t a, b;
    #pragma unroll
    for (int j=0;j<8;++j){ a[j]=f2b(tile[kk0+j][nn]); b[j]=f2b(tile[kk0+8+j][nn]); }
    unsigned short* dst = out + (size_t)(n0+nn)*1024 + k0 + kk0;
    *(ushort8_t*)dst = a;
    *(ushort8_t*)(dst+8) = b;
  }
}

// ---------------- h0 -> hs[0] bf16 ------------------------------------------
__global__ void k_init(const float* __restrict__ h0, unsigned short* __restrict__ hs){
  const int i = blockIdx.x*256 + threadIdx.x;
  hs[i] = f2b(h0[i]);
}

// ---------------- sentinel-fill hs[1..1024] ---------------------------------
__global__ void k_fill(unsigned* __restrict__ hsw){
  const size_t i = (size_t)blockIdx.x*256 + threadIdx.x;   // 2,097,152 threads
  uint4_t v = (uint4_t){SENT, SENT, SENT, SENT};
  *(uint4_t*)(hsw + 8192 + i*4) = v;                       // slot1 starts at word 8192
}

// ---------------- x projections: xg[t][g][n][b] = x @ Wx + bx (bf16 out) ----
__global__ __launch_bounds__(256,2) void k_xproj(
    const float* __restrict__ xF, const float* __restrict__ xI,
    const float* __restrict__ xZ, const float* __restrict__ xO,
    const float* __restrict__ bF, const float* __restrict__ bI,
    const float* __restrict__ bZ, const float* __restrict__ bO,
    const unsigned short* __restrict__ Wt,   // [4][n][k] bf16
    unsigned short* __restrict__ xg)
{
  const int g  = blockIdx.z;
  const int tm = blockIdx.x, tn = blockIdx.y;
  const float* X  = (g==0)?xF:(g==1)?xI:(g==2)?xZ:xO;
  const float* Bp = (g==0)?bF:(g==1)?bI:(g==2)?bZ:bO;
  const unsigned short* Wg = Wt + (size_t)g*1024*1024;

  __shared__ unsigned short Asm[128*32];
  __shared__ unsigned short Bsm[128*32];

  const int tid  = threadIdx.x;
  const int lane = tid & 63, wv = tid >> 6;
  const int l15  = lane & 15, lg = lane >> 4;
  const int wy   = wv >> 1,  wx = wv & 1;

  const int rr = tid >> 1, kq = tid & 1;
  const int ar = tm*128 + rr;
  const int ab = ar & 15, as_ = ar >> 4;
  const float* aptr = X + ((size_t)ab*1024 + as_)*1024 + kq*16;
  const unsigned short* bp_ = Wg + (size_t)(tn*128 + rr)*1024 + kq*16;
  const int s0 = kq*2;
  unsigned short* aw0 = &Asm[rr*32 + (((s0  ) ^ (rr&3))<<3)];
  unsigned short* aw1 = &Asm[rr*32 + (((s0+1) ^ (rr&3))<<3)];
  unsigned short* bw0 = &Bsm[rr*32 + (((s0  ) ^ (rr&3))<<3)];
  unsigned short* bw1 = &Bsm[rr*32 + (((s0+1) ^ (rr&3))<<3)];

  f32x4 acc[4][4];
  #pragma unroll
  for (int m=0;m<4;++m)
    #pragma unroll
    for (int q=0;q<4;++q) acc[m][q] = (f32x4){0.f,0.f,0.f,0.f};

  for (int k0=0; k0<1024; k0+=32){
    const float* ap = aptr + k0;
    f32x4 v0 = *(const f32x4*)(ap + 0);
    f32x4 v1 = *(const f32x4*)(ap + 4);
    f32x4 v2 = *(const f32x4*)(ap + 8);
    f32x4 v3 = *(const f32x4*)(ap + 12);
    ushort8_t pa, pb;
    #pragma unroll
    for (int j=0;j<4;++j){ pa[j]=f2b(v0[j]); pa[4+j]=f2b(v1[j]); pb[j]=f2b(v2[j]); pb[4+j]=f2b(v3[j]); }
    *(ushort8_t*)aw0 = pa;
    *(ushort8_t*)aw1 = pb;
    ushort8_t q0 = *(const ushort8_t*)(bp_ + k0);
    ushort8_t q1 = *(const ushort8_t*)(bp_ + k0 + 8);
    *(ushort8_t*)bw0 = q0;
    *(ushort8_t*)bw1 = q1;
    __syncthreads();

    short8 af[4], bf_[4];
    #pragma unroll
    for (int m=0;m<4;++m){
      int row = wy*64 + m*16 + l15;
      af[m] = *(const short8*)&Asm[row*32 + ((lg ^ (row&3))<<3)];
    }
    #pragma unroll
    for (int q=0;q<4;++q){
      int row = wx*64 + q*16 + l15;
      bf_[q] = *(const short8*)&Bsm[row*32 + ((lg ^ (row&3))<<3)];
    }
    #pragma unroll
    for (int m=0;m<4;++m)
      #pragma unroll
      for (int q=0;q<4;++q)
        acc[m][q] = __builtin_amdgcn_mfma_f32_16x16x32_bf16(af[m], bf_[q], acc[m][q], 0,0,0);
    __syncthreads();
  }

  #pragma unroll
  for (int m=0;m<4;++m){
    const int t = tm*8 + wy*4 + m;
    #pragma unroll
    for (int q=0;q<4;++q){
      const int n = tn*128 + wx*64 + q*16 + l15;
      const float bias = Bp[n];
      f32x4 v = acc[m][q];
      ushort4_t pk;
      #pragma unroll
      for (int r=0;r<4;++r) pk[r] = f2b(v[r] + bias);
      *(ushort4_t*)(xg + (size_t)((t*4+g)*1024 + n)*16 + lg*4) = pk;
    }
  }
}

// ---------------- persistent recurrence (flag + write-through + sentinel) ---
// 64 WGs; WG wg owns output cols [wg*16,+16); wave wv holds K-slice [wv*256,+256)
// in 128 weight VGPRs. Producer: data stores sc0sc1 -> vmcnt(0) -> flag store.
// Consumer: poll 16 flags (1 dword/lane) -> single-pass dwordx4 data load ->
// sentinel backstop (rare retry). No fences, no L2 invalidates, no congestion.
__global__ __launch_bounds__(256,1) void k_recur(
    const unsigned short* __restrict__ WtR,   // [4][1024 n][1024 k] bf16 (Fh,Ih,Zh,Oh)
    const float* __restrict__ bfh, const float* __restrict__ bih,
    const float* __restrict__ bzh, const float* __restrict__ boh,
    const float* __restrict__ c0,
    const unsigned short* __restrict__ xg,
    unsigned short* __restrict__ hs,
    unsigned* __restrict__ flags,
    float* __restrict__ oc, float* __restrict__ oh)
{
  const int wg   = blockIdx.x;          // 0..63
  const int tid  = threadIdx.x;
  const int wv   = tid >> 6, lane = tid & 63;
  const int l15  = lane & 15, lg = lane >> 4;
  const int n    = wg*16 + l15;

  // register-resident recurrent weights from pre-transposed bf16 (coalesced)
  short8 wf[4][8];
  #pragma unroll
  for (int g=0; g<4; ++g){
    const unsigned short* wp = WtR + (size_t)g*1048576 + (size_t)n*1024 + wv*256 + lg*8;
    #pragma unroll
    for (int c=0; c<8; ++c)
      wf[g][c] = *(const short8*)(wp + c*32);
  }

  float cst[4]; float bias[4];
  if (wv == 0){
    bias[0]=bfh[n]; bias[1]=bih[n]; bias[2]=bzh[n]; bias[3]=boh[n];
    #pragma unroll
    for (int r=0;r<4;++r) cst[r] = c0[(size_t)(lg*4+r)*1024 + n];
  }
  __shared__ f32x4 part[3][4][64];

  unsigned* hsw = (unsigned*)hs;
  unsigned* flagp = flags + (wv*16 + l15)*FSTRIDE;   // used by lanes with lane<16

  for (int t=0; t<1024; ++t){
    // prefetch xg[t] (plain cached loads; in flight during the flag wait)
    short4_t xq[4];
    if (wv == 0){
      #pragma unroll
      for (int g=0; g<4; ++g)
        xq[g] = *(const short4_t*)(xg + (size_t)((t*4+g)*1024 + n)*16 + lg*4);
    }

    // wait for this wave's 16 producers (1 dword per lane per retry)
    {
      unsigned v = 0xFFFFFFFFu;
      for(;;){
        if (lane < 16) v = ld_u32_mall(flagp);
        if (__all((int)(v >= (unsigned)t))) break;
      }
    }

    // single-pass A-fragment load from coherence point
    const unsigned short* hp = hs + (size_t)t*16384 + (size_t)l15*1024 + wv*256 + lg*8;
    short8 a[8];
    ld_h8_mall(hp, a);
    // sentinel backstop: if the flag outran the data (rare), re-load
    {
      bool bad = false;
      #pragma unroll
      for (int c=0;c<8;++c){
        uint4_t q = __builtin_bit_cast(uint4_t, a[c]);
        bad |= (q[0]==SENT)|(q[1]==SENT)|(q[2]==SENT)|(q[3]==SENT);
      }
      while (__any(bad)){
        ld_h8_mall(hp, a);
        bad = false;
        #pragma unroll
        for (int c=0;c<8;++c){
          uint4_t q = __builtin_bit_cast(uint4_t, a[c]);
          bad |= (q[0]==SENT)|(q[1]==SENT)|(q[2]==SENT)|(q[3]==SENT);
        }
      }
    }

    f32x4 acc[4];
    #pragma unroll
    for (int g=0;g<4;++g) acc[g] = (f32x4){0.f,0.f,0.f,0.f};
    #pragma unroll
    for (int c=0;c<8;++c){
      acc[0] = __builtin_amdgcn_mfma_f32_16x16x32_bf16(a[c], wf[0][c], acc[0], 0,0,0);
      acc[1] = __builtin_amdgcn_mfma_f32_16x16x32_bf16(a[c], wf[1][c], acc[1], 0,0,0);
      acc[2] = __builtin_amdgcn_mfma_f32_16x16x32_bf16(a[c], wf[2][c], acc[2], 0,0,0);
      acc[3] = __builtin_amdgcn_mfma_f32_16x16x32_bf16(a[c], wf[3][c], acc[3], 0,0,0);
    }
    if (wv > 0){
      #pragma unroll
      for (int g=0;g<4;++g) part[wv-1][g][lane] = acc[g];
    }
    __syncthreads();
    if (wv == 0){
      #pragma unroll
      for (int p=0;p<3;++p)
        #pragma unroll
        for (int g=0;g<4;++g) acc[g] += part[p][g][lane];

      float hv[4];
      #pragma unroll
      for (int r=0;r<4;++r){
        float pf = acc[0][r] + b2f((unsigned short)xq[0][r]) + bias[0];
        float pi = acc[1][r] + b2f((unsigned short)xq[1][r]) + bias[1];
        float pz = acc[2][r] + b2f((unsigned short)xq[2][r]) + bias[2];
        float po = acc[3][r] + b2f((unsigned short)xq[3][r]) + bias[3];
        float fg = sigm(pf), ig = sigm(pi), zg = tanh_(pz), og = sigm(po);
        float cn = fg*cst[r] + ig*zg;
        cst[r] = cn;
        hv[r] = og * tanh_(cn);
      }
      // pack bf16 pairs across lane^1 (cols n even/odd); even lanes store u32
      unsigned wrd[4];
      #pragma unroll
      for (int r=0;r<4;++r){
        unsigned m  = (unsigned)f2b(hv[r]);
        unsigned nb = (unsigned)__shfl_xor(m, 1);
        wrd[r] = m | (nb << 16);
      }
      if ((l15 & 1) == 0){
        unsigned* pw = hsw + (size_t)(t+1)*8192 + lg*2048 + (n >> 1);
        st_h4_mall(pw, wrd[0], wrd[1], wrd[2], wrd[3]);
      }
      if (t == 1023){
        #pragma unroll
        for (int r=0;r<4;++r){
          oc[(size_t)(lg*4+r)*1024 + n] = cst[r];
          oh[(size_t)(lg*4+r)*1024 + n] = hv[r];
        }
      }
      // drain data stores to coherence point, then publish flag
      asm volatile("s_waitcnt vmcnt(0)" ::: "memory");
      if (lane == 0) st_flag_mall(flags + wg*FSTRIDE, (unsigned)(t+1));
    }
    __syncthreads();   // 'part' free for next step's writers
  }
}

// ---------------- post projection: y[b][s][n] = hs[1..] @ Wpost + bpost -----
__global__ __launch_bounds__(256,2) void k_post(
    const unsigned short* __restrict__ hs,
    const unsigned short* __restrict__ Wt,   // post slice at +4M
    const float* __restrict__ bpost,
    float* __restrict__ y)
{
  const int tm = blockIdx.x, tn = blockIdx.y;
  __shared__ unsigned short Asm[128*32];
  __shared__ unsigned short Bsm[128*32];

  const int tid  = threadIdx.x;
  const int lane = tid & 63, wv = tid >> 6;
  const int l15  = lane & 15, lg = lane >> 4;
  const int wy   = wv >> 1,  wx = wv & 1;

  const int rr = tid >> 1, kq = tid & 1;
  const unsigned short* aptr = hs + 16384 + (size_t)(tm*128 + rr)*1024 + kq*16;
  const unsigned short* bp_  = Wt + (size_t)4*1024*1024 + (size_t)(tn*128 + rr)*1024 + kq*16;
  const int s0 = kq*2;
  unsigned short* aw0 = &Asm[rr*32 + (((s0  ) ^ (rr&3))<<3)];
  unsigned short* aw1 = &Asm[rr*32 + (((s0+1) ^ (rr&3))<<3)];
  unsigned short* bw0 = &Bsm[rr*32 + (((s0  ) ^ (rr&3))<<3)];
  unsigned short* bw1 = &Bsm[rr*32 + (((s0+1) ^ (rr&3))<<3)];

  f32x4 acc[4][4];
  #pragma unroll
  for (int m=0;m<4;++m)
    #pragma unroll
    for (int q=0;q<4;++q) acc[m][q] = (f32x4){0.f,0.f,0.f,0.f};

  for (int k0=0; k0<1024; k0+=32){
    ushort8_t a0 = *(const ushort8_t*)(aptr + k0);
    ushort8_t a1 = *(const ushort8_t*)(aptr + k0 + 8);
    *(ushort8_t*)aw0 = a0;
    *(ushort8_t*)aw1 = a1;
    ushort8_t q0 = *(const ushort8_t*)(bp_ + k0);
    ushort8_t q1 = *(const ushort8_t*)(bp_ + k0 + 8);
    *(ushort8_t*)bw0 = q0;
    *(ushort8_t*)bw1 = q1;
    __syncthreads();

    short8 af[4], bf_[4];
    #pragma unroll
    for (int m=0;m<4;++m){
      int row = wy*64 + m*16 + l15;
      af[m] = *(const short8*)&Asm[row*32 + ((lg ^ (row&3))<<3)];
    }
    #pragma unroll
    for (int q=0;q<4;++q){
      int row = wx*64 + q*16 + l15;
      bf_[q] = *(const short8*)&Bsm[row*32 + ((lg ^ (row&3))<<3)];
    }
    #pragma unroll
    for (int m=0;m<4;++m)
      #pragma unroll
      for (int q=0;q<4;++q)
        acc[m][q] = __builtin_amdgcn_mfma_f32_16x16x32_bf16(af[m], bf_[q], acc[m][q], 0,0,0);
    __syncthreads();
  }

  #pragma unroll
  for (int m=0;m<4;++m){
    const int s = tm*8 + wy*4 + m;
    #pragma unroll
    for (int q=0;q<4;++q){
      const int n = tn*128 + wx*64 + q*16 + l15;
      const float bias = bpost[n];
      f32x4 v = acc[m][q];
      #pragma unroll
      for (int r=0;r<4;++r){
        const int b = lg*4 + r;
        y[((size_t)b << 20) + ((size_t)s << 10) + n] = v[r] + bias;
      }
    }
  }
}

extern "C" void kernel_launch(void* const* d_in, const int* in_sizes, int n_in,
                              void* d_out, int out_size, void* d_ws, size_t ws_size,
                              hipStream_t stream)
{
  const float* f_in = (const float*)d_in[0];
  const float* i_in = (const float*)d_in[1];
  const float* z_in = (const float*)d_in[2];
  const float* o_in = (const float*)d_in[3];
  const float* c0   = (const float*)d_in[4];
  const float* h0   = (const float*)d_in[5];
  const float* W_Fx = (const float*)d_in[6];  const float* b_Fx = (const float*)d_in[7];
  const float* W_Ix = (const float*)d_in[8];  const float* b_Ix = (const float*)d_in[9];
  const float* W_Zx = (const float*)d_in[10]; const float* b_Zx = (const float*)d_in[11];
  const float* W_Ox = (const float*)d_in[12]; const float* b_Ox = (const float*)d_in[13];
  const float* W_Fh = (const float*)d_in[14]; const float* b_Fh = (const float*)d_in[15];
  const float* W_Ih = (const float*)d_in[16]; const float* b_Ih = (const float*)d_in[17];
  const float* W_Zh = (const float*)d_in[18]; const float* b_Zh = (const float*)d_in[19];
  const float* W_Oh = (const float*)d_in[20]; const float* b_Oh = (const float*)d_in[21];
  const float* W_post = (const float*)d_in[22]; const float* b_post = (const float*)d_in[23];

  char* ws = (char*)d_ws;
  unsigned short* xg    = (unsigned short*)(ws);
  unsigned short* hs    = (unsigned short*)(ws + XG_BYTES);
  unsigned*       flags = (unsigned*)(ws + FLAGS_OFF);
  unsigned short* wt    = (unsigned short*)(ws + WT_OFF);

  float* y  = (float*)d_out;
  float* oc = y + 16777216;   // 16*1024*1024
  float* oh = oc + 16384;

  hipMemsetAsync(flags, 0, 8192, stream);
  k_prep<<<dim3(16,16,9), 256, 0, stream>>>(W_Fx, W_Ix, W_Zx, W_Ox, W_post,
                                            W_Fh, W_Ih, W_Zh, W_Oh, wt);
  k_init<<<64, 256, 0, stream>>>(h0, hs);
  k_fill<<<8192, 256, 0, stream>>>((unsigned*)hs);
  k_xproj<<<dim3(128,8,4), 256, 0, stream>>>(f_in, i_in, z_in, o_in,
                                             b_Fx, b_Ix, b_Zx, b_Ox, wt, xg);
  k_recur<<<64, 256, 0, stream>>>(wt + (size_t)5*1024*1024,
                                  b_Fh, b_Ih, b_Zh, b_Oh,
                                  c0, xg, hs, flags, oc, oh);
  k_post<<<dim3(128,8), 256, 0, stream>>>(hs, wt, b_post, y);
}

// Round 5
// 3610.245 us; speedup vs baseline: 2.4754x; 1.2299x over previous
//
#include <hip/hip_runtime.h>
#include <stdint.h>
#include <stddef.h>

typedef __attribute__((ext_vector_type(8))) short short8;
typedef __attribute__((ext_vector_type(4))) short short4_t;
typedef __attribute__((ext_vector_type(8))) unsigned short ushort8_t;
typedef __attribute__((ext_vector_type(4))) unsigned short ushort4_t;
typedef __attribute__((ext_vector_type(4))) float f32x4;
typedef __attribute__((ext_vector_type(4))) unsigned uint4_t;

// workspace layout (bytes)
#define XG_BYTES  (134217728ull)          // xg: [1024 t][4 g][1024 n][16 b] bf16
#define HS_BYTES  (33587200ull)           // hs: [1025 t][16 b][1024 k] bf16
#define FLAGS_OFF (XG_BYTES + HS_BYTES)   // (kept for layout compat, unused)
#define WT_OFF    (FLAGS_OFF + 32768ull)  // Wt: [9][1024 n][1024 k] bf16

#define SENT 0x7FC07FC0u                  // bf16 NaN pair — h is finite, never equals this

__device__ __forceinline__ unsigned short f2b(float f){
  unsigned u = __builtin_bit_cast(unsigned, f);
  u += 0x7fffu + ((u >> 16) & 1u);
  return (unsigned short)(u >> 16);
}
__device__ __forceinline__ float b2f(unsigned short b){
  unsigned u = ((unsigned)b) << 16;
  return __builtin_bit_cast(float, u);
}
__device__ __forceinline__ float sigm(float x){ return 1.0f / (1.0f + __expf(-x)); }
__device__ __forceinline__ float tanh_(float x){ return 2.0f / (1.0f + __expf(-2.0f*x)) - 1.0f; }

// ---- coherence-point (MALL) primitives: sc0 sc1 = bypass L1 and L2 --------
__device__ __forceinline__ void ld_h8_mall(const unsigned short* p, short8* a){
  asm volatile(
    "global_load_dwordx4 %0, %8, off sc0 sc1\n\t"
    "global_load_dwordx4 %1, %8, off offset:64 sc0 sc1\n\t"
    "global_load_dwordx4 %2, %8, off offset:128 sc0 sc1\n\t"
    "global_load_dwordx4 %3, %8, off offset:192 sc0 sc1\n\t"
    "global_load_dwordx4 %4, %8, off offset:256 sc0 sc1\n\t"
    "global_load_dwordx4 %5, %8, off offset:320 sc0 sc1\n\t"
    "global_load_dwordx4 %6, %8, off offset:384 sc0 sc1\n\t"
    "global_load_dwordx4 %7, %8, off offset:448 sc0 sc1\n\t"
    "s_waitcnt vmcnt(0)"
    : "=&v"(a[0]), "=&v"(a[1]), "=&v"(a[2]), "=&v"(a[3]),
      "=&v"(a[4]), "=&v"(a[5]), "=&v"(a[6]), "=&v"(a[7])
    : "v"(p) : "memory");
}
__device__ __forceinline__ void st_u32_mall(unsigned* p, unsigned v){
  asm volatile("global_store_dword %0, %1, off sc0 sc1"
               :: "v"(p), "v"(v) : "memory");
}

// ---------------- weight transpose+convert: W[k][n] f32 -> Wt[n][k] bf16 ----
__global__ __launch_bounds__(256) void k_prep(
    const float* __restrict__ w0, const float* __restrict__ w1,
    const float* __restrict__ w2, const float* __restrict__ w3,
    const float* __restrict__ w4, const float* __restrict__ w5,
    const float* __restrict__ w6, const float* __restrict__ w7,
    const float* __restrict__ w8, unsigned short* __restrict__ wt)
{
  const int z = blockIdx.z;
  const float* W = (z==0)?w0:(z==1)?w1:(z==2)?w2:(z==3)?w3:(z==4)?w4:
                   (z==5)?w5:(z==6)?w6:(z==7)?w7:w8;
  unsigned short* out = wt + (size_t)z*1024*1024;
  __shared__ float tile[64][65];
  const int k0 = blockIdx.x*64, n0 = blockIdx.y*64;
  const int tid = threadIdx.x;
  {
    const int kk = tid >> 2, nn0 = (tid & 3) * 16;
    const float* src = W + (size_t)(k0+kk)*1024 + n0 + nn0;
    #pragma unroll
    for (int j=0;j<16;j+=4){
      f32x4 v = *(const f32x4*)(src + j);
      tile[kk][nn0+j+0]=v[0]; tile[kk][nn0+j+1]=v[1];
      tile[kk][nn0+j+2]=v[2]; tile[kk][nn0+j+3]=v[3];
    }
  }
  __syncthreads();
  {
    const int nn = tid >> 2, kk0 = (tid & 3) * 16;
    ushort8_t a, b;
    #pragma unroll
    for (int j=0;j<8;++j){ a[j]=f2b(tile[kk0+j][nn]); b[j]=f2b(tile[kk0+8+j][nn]); }
    unsigned short* dst = out + (size_t)(n0+nn)*1024 + k0 + kk0;
    *(ushort8_t*)dst = a;
    *(ushort8_t*)(dst+8) = b;
  }
}

// ---------------- h0 -> hs[0] bf16 ------------------------------------------
__global__ void k_init(const float* __restrict__ h0, unsigned short* __restrict__ hs){
  const int i = blockIdx.x*256 + threadIdx.x;
  hs[i] = f2b(h0[i]);
}

// ---------------- sentinel-fill hs[1..1024] ---------------------------------
__global__ void k_fill(unsigned* __restrict__ hsw){
  const size_t i = (size_t)blockIdx.x*256 + threadIdx.x;   // 2,097,152 threads
  uint4_t v = (uint4_t){SENT, SENT, SENT, SENT};
  *(uint4_t*)(hsw + 8192 + i*4) = v;                       // slot1 starts at word 8192
}

// ---------------- x projections: xg[t][g][n][b] = x @ Wx + bx (bf16 out) ----
__global__ __launch_bounds__(256,2) void k_xproj(
    const float* __restrict__ xF, const float* __restrict__ xI,
    const float* __restrict__ xZ, const float* __restrict__ xO,
    const float* __restrict__ bF, const float* __restrict__ bI,
    const float* __restrict__ bZ, const float* __restrict__ bO,
    const unsigned short* __restrict__ Wt,   // [4][n][k] bf16
    unsigned short* __restrict__ xg)
{
  const int g  = blockIdx.z;
  const int tm = blockIdx.x, tn = blockIdx.y;
  const float* X  = (g==0)?xF:(g==1)?xI:(g==2)?xZ:xO;
  const float* Bp = (g==0)?bF:(g==1)?bI:(g==2)?bZ:bO;
  const unsigned short* Wg = Wt + (size_t)g*1024*1024;

  __shared__ unsigned short Asm[128*32];
  __shared__ unsigned short Bsm[128*32];

  const int tid  = threadIdx.x;
  const int lane = tid & 63, wv = tid >> 6;
  const int l15  = lane & 15, lg = lane >> 4;
  const int wy   = wv >> 1,  wx = wv & 1;

  const int rr = tid >> 1, kq = tid & 1;
  const int ar = tm*128 + rr;
  const int ab = ar & 15, as_ = ar >> 4;
  const float* aptr = X + ((size_t)ab*1024 + as_)*1024 + kq*16;
  const unsigned short* bp_ = Wg + (size_t)(tn*128 + rr)*1024 + kq*16;
  const int s0 = kq*2;
  unsigned short* aw0 = &Asm[rr*32 + (((s0  ) ^ (rr&3))<<3)];
  unsigned short* aw1 = &Asm[rr*32 + (((s0+1) ^ (rr&3))<<3)];
  unsigned short* bw0 = &Bsm[rr*32 + (((s0  ) ^ (rr&3))<<3)];
  unsigned short* bw1 = &Bsm[rr*32 + (((s0+1) ^ (rr&3))<<3)];

  f32x4 acc[4][4];
  #pragma unroll
  for (int m=0;m<4;++m)
    #pragma unroll
    for (int q=0;q<4;++q) acc[m][q] = (f32x4){0.f,0.f,0.f,0.f};

  for (int k0=0; k0<1024; k0+=32){
    const float* ap = aptr + k0;
    f32x4 v0 = *(const f32x4*)(ap + 0);
    f32x4 v1 = *(const f32x4*)(ap + 4);
    f32x4 v2 = *(const f32x4*)(ap + 8);
    f32x4 v3 = *(const f32x4*)(ap + 12);
    ushort8_t pa, pb;
    #pragma unroll
    for (int j=0;j<4;++j){ pa[j]=f2b(v0[j]); pa[4+j]=f2b(v1[j]); pb[j]=f2b(v2[j]); pb[4+j]=f2b(v3[j]); }
    *(ushort8_t*)aw0 = pa;
    *(ushort8_t*)aw1 = pb;
    ushort8_t q0 = *(const ushort8_t*)(bp_ + k0);
    ushort8_t q1 = *(const ushort8_t*)(bp_ + k0 + 8);
    *(ushort8_t*)bw0 = q0;
    *(ushort8_t*)bw1 = q1;
    __syncthreads();

    short8 af[4], bf_[4];
    #pragma unroll
    for (int m=0;m<4;++m){
      int row = wy*64 + m*16 + l15;
      af[m] = *(const short8*)&Asm[row*32 + ((lg ^ (row&3))<<3)];
    }
    #pragma unroll
    for (int q=0;q<4;++q){
      int row = wx*64 + q*16 + l15;
      bf_[q] = *(const short8*)&Bsm[row*32 + ((lg ^ (row&3))<<3)];
    }
    #pragma unroll
    for (int m=0;m<4;++m)
      #pragma unroll
      for (int q=0;q<4;++q)
        acc[m][q] = __builtin_amdgcn_mfma_f32_16x16x32_bf16(af[m], bf_[q], acc[m][q], 0,0,0);
    __syncthreads();
  }

  #pragma unroll
  for (int m=0;m<4;++m){
    const int t = tm*8 + wy*4 + m;
    #pragma unroll
    for (int q=0;q<4;++q){
      const int n = tn*128 + wx*64 + q*16 + l15;
      const float bias = Bp[n];
      f32x4 v = acc[m][q];
      ushort4_t pk;
      #pragma unroll
      for (int r=0;r<4;++r) pk[r] = f2b(v[r] + bias);
      *(ushort4_t*)(xg + (size_t)((t*4+g)*1024 + n)*16 + lg*4) = pk;
    }
  }
}

// ---------------- persistent recurrence (speculative load + sentinel) -------
// 64 WGs; WG wg owns output cols [wg*16,+16); wave wv holds K-slice [wv*256,+256)
// in 128 weight VGPRs. Producer: gate on ALL waves redundantly, wave wv stores
// row-quarter r=wv (1 dword/active lane, no drain, no flag). Consumer: issue
// bulk dwordx4 load speculatively; sentinel words trigger pipelined re-loads.
// One MALL round-trip per step in steady state.
__global__ __launch_bounds__(256,1) void k_recur(
    const unsigned short* __restrict__ WtR,   // [4][1024 n][1024 k] bf16 (Fh,Ih,Zh,Oh)
    const float* __restrict__ bfh, const float* __restrict__ bih,
    const float* __restrict__ bzh, const float* __restrict__ boh,
    const float* __restrict__ c0,
    const unsigned short* __restrict__ xg,
    unsigned short* __restrict__ hs,
    float* __restrict__ oc, float* __restrict__ oh)
{
  const int wg   = blockIdx.x;          // 0..63
  const int tid  = threadIdx.x;
  const int wv   = tid >> 6, lane = tid & 63;
  const int l15  = lane & 15, lg = lane >> 4;
  const int n    = wg*16 + l15;

  // register-resident recurrent weights from pre-transposed bf16 (coalesced)
  short8 wf[4][8];
  #pragma unroll
  for (int g=0; g<4; ++g){
    const unsigned short* wp = WtR + (size_t)g*1048576 + (size_t)n*1024 + wv*256 + lg*8;
    #pragma unroll
    for (int c=0; c<8; ++c)
      wf[g][c] = *(const short8*)(wp + c*32);
  }

  // gating state on ALL waves (redundant, identical math -> identical values)
  float cst[4]; float bias[4];
  bias[0]=bfh[n]; bias[1]=bih[n]; bias[2]=bzh[n]; bias[3]=boh[n];
  #pragma unroll
  for (int r=0;r<4;++r) cst[r] = c0[(size_t)(lg*4+r)*1024 + n];

  __shared__ f32x4 part[2][4][4][64];   // [buf][wave][gate][lane]

  unsigned* hsw = (unsigned*)hs;

  for (int t=0; t<1024; ++t){
    // xg[t] prefetch (plain cached loads; in flight with the bulk load)
    short4_t xq[4];
    #pragma unroll
    for (int g=0; g<4; ++g)
      xq[g] = *(const short4_t*)(xg + (size_t)((t*4+g)*1024 + n)*16 + lg*4);

    // speculative bulk A-fragment load; sentinel words -> pipelined retry
    const unsigned short* hp = hs + (size_t)t*16384 + (size_t)l15*1024 + wv*256 + lg*8;
    short8 a[8];
    ld_h8_mall(hp, a);
    for(;;){
      bool bad = false;
      #pragma unroll
      for (int c=0;c<8;++c){
        uint4_t q = __builtin_bit_cast(uint4_t, a[c]);
        bad |= (q[0]==SENT)|(q[1]==SENT)|(q[2]==SENT)|(q[3]==SENT);
      }
      if (!__any(bad)) break;
      __builtin_amdgcn_s_sleep(1);
      ld_h8_mall(hp, a);
    }

    f32x4 acc[4];
    #pragma unroll
    for (int g=0;g<4;++g) acc[g] = (f32x4){0.f,0.f,0.f,0.f};
    #pragma unroll
    for (int c=0;c<8;++c){
      acc[0] = __builtin_amdgcn_mfma_f32_16x16x32_bf16(a[c], wf[0][c], acc[0], 0,0,0);
      acc[1] = __builtin_amdgcn_mfma_f32_16x16x32_bf16(a[c], wf[1][c], acc[1], 0,0,0);
      acc[2] = __builtin_amdgcn_mfma_f32_16x16x32_bf16(a[c], wf[2][c], acc[2], 0,0,0);
      acc[3] = __builtin_amdgcn_mfma_f32_16x16x32_bf16(a[c], wf[3][c], acc[3], 0,0,0);
    }
    const int pb = t & 1;
    #pragma unroll
    for (int g=0;g<4;++g) part[pb][wv][g][lane] = acc[g];
    __syncthreads();   // single sync per step (double-buffered partials)

    f32x4 r_[4];
    #pragma unroll
    for (int g=0;g<4;++g){
      f32x4 s0 = part[pb][0][g][lane];
      f32x4 s1 = part[pb][1][g][lane];
      f32x4 s2 = part[pb][2][g][lane];
      f32x4 s3 = part[pb][3][g][lane];
      r_[g] = (s0 + s1) + (s2 + s3);
    }

    float hv[4];
    // compute own row-quarter (r = wv) FIRST and store it immediately
    {
      const int r = wv;
      float pf = r_[0][r] + b2f((unsigned short)xq[0][r]) + bias[0];
      float pi = r_[1][r] + b2f((unsigned short)xq[1][r]) + bias[1];
      float pz = r_[2][r] + b2f((unsigned short)xq[2][r]) + bias[2];
      float po = r_[3][r] + b2f((unsigned short)xq[3][r]) + bias[3];
      float fg = sigm(pf), ig = sigm(pi), zg = tanh_(pz), og = sigm(po);
      float cn = fg*cst[r] + ig*zg;
      cst[r] = cn;
      hv[r] = og * tanh_(cn);
      unsigned m  = (unsigned)f2b(hv[r]);
      unsigned nb = (unsigned)__shfl_xor(m, 1);
      if ((l15 & 1) == 0){
        unsigned word = m | (nb << 16);
        unsigned* pw = hsw + (size_t)(t+1)*8192 + (size_t)(lg*4+wv)*512 + (n >> 1);
        st_u32_mall(pw, word);   // no drain, no flag — sentinel is the signal
      }
    }
    // remaining row-quarters (cell-state carry only)
    #pragma unroll
    for (int r=0;r<4;++r){
      if (r == wv) continue;
      float pf = r_[0][r] + b2f((unsigned short)xq[0][r]) + bias[0];
      float pi = r_[1][r] + b2f((unsigned short)xq[1][r]) + bias[1];
      float pz = r_[2][r] + b2f((unsigned short)xq[2][r]) + bias[2];
      float po = r_[3][r] + b2f((unsigned short)xq[3][r]) + bias[3];
      float fg = sigm(pf), ig = sigm(pi), zg = tanh_(pz), og = sigm(po);
      float cn = fg*cst[r] + ig*zg;
      cst[r] = cn;
      hv[r] = og * tanh_(cn);
    }
    if (t == 1023 && wv == 0){
      #pragma unroll
      for (int r=0;r<4;++r){
        oc[(size_t)(lg*4+r)*1024 + n] = cst[r];
        oh[(size_t)(lg*4+r)*1024 + n] = hv[r];
      }
    }
  }
}

// ---------------- post projection: y[b][s][n] = hs[1..] @ Wpost + bpost -----
__global__ __launch_bounds__(256,2) void k_post(
    const unsigned short* __restrict__ hs,
    const unsigned short* __restrict__ Wt,   // post slice at +4M
    const float* __restrict__ bpost,
    float* __restrict__ y)
{
  const int tm = blockIdx.x, tn = blockIdx.y;
  __shared__ unsigned short Asm[128*32];
  __shared__ unsigned short Bsm[128*32];

  const int tid  = threadIdx.x;
  const int lane = tid & 63, wv = tid >> 6;
  const int l15  = lane & 15, lg = lane >> 4;
  const int wy   = wv >> 1,  wx = wv & 1;

  const int rr = tid >> 1, kq = tid & 1;
  const unsigned short* aptr = hs + 16384 + (size_t)(tm*128 + rr)*1024 + kq*16;
  const unsigned short* bp_  = Wt + (size_t)4*1024*1024 + (size_t)(tn*128 + rr)*1024 + kq*16;
  const int s0 = kq*2;
  unsigned short* aw0 = &Asm[rr*32 + (((s0  ) ^ (rr&3))<<3)];
  unsigned short* aw1 = &Asm[rr*32 + (((s0+1) ^ (rr&3))<<3)];
  unsigned short* bw0 = &Bsm[rr*32 + (((s0  ) ^ (rr&3))<<3)];
  unsigned short* bw1 = &Bsm[rr*32 + (((s0+1) ^ (rr&3))<<3)];

  f32x4 acc[4][4];
  #pragma unroll
  for (int m=0;m<4;++m)
    #pragma unroll
    for (int q=0;q<4;++q) acc[m][q] = (f32x4){0.f,0.f,0.f,0.f};

  for (int k0=0; k0<1024; k0+=32){
    ushort8_t a0 = *(const ushort8_t*)(aptr + k0);
    ushort8_t a1 = *(const ushort8_t*)(aptr + k0 + 8);
    *(ushort8_t*)aw0 = a0;
    *(ushort8_t*)aw1 = a1;
    ushort8_t q0 = *(const ushort8_t*)(bp_ + k0);
    ushort8_t q1 = *(const ushort8_t*)(bp_ + k0 + 8);
    *(ushort8_t*)bw0 = q0;
    *(ushort8_t*)bw1 = q1;
    __syncthreads();

    short8 af[4], bf_[4];
    #pragma unroll
    for (int m=0;m<4;++m){
      int row = wy*64 + m*16 + l15;
      af[m] = *(const short8*)&Asm[row*32 + ((lg ^ (row&3))<<3)];
    }
    #pragma unroll
    for (int q=0;q<4;++q){
      int row = wx*64 + q*16 + l15;
      bf_[q] = *(const short8*)&Bsm[row*32 + ((lg ^ (row&3))<<3)];
    }
    #pragma unroll
    for (int m=0;m<4;++m)
      #pragma unroll
      for (int q=0;q<4;++q)
        acc[m][q] = __builtin_amdgcn_mfma_f32_16x16x32_bf16(af[m], bf_[q], acc[m][q], 0,0,0);
    __syncthreads();
  }

  #pragma unroll
  for (int m=0;m<4;++m){
    const int s = tm*8 + wy*4 + m;
    #pragma unroll
    for (int q=0;q<4;++q){
      const int n = tn*128 + wx*64 + q*16 + l15;
      const float bias = bpost[n];
      f32x4 v = acc[m][q];
      #pragma unroll
      for (int r=0;r<4;++r){
        const int b = lg*4 + r;
        y[((size_t)b << 20) + ((size_t)s << 10) + n] = v[r] + bias;
      }
    }
  }
}

extern "C" void kernel_launch(void* const* d_in, const int* in_sizes, int n_in,
                              void* d_out, int out_size, void* d_ws, size_t ws_size,
                              hipStream_t stream)
{
  const float* f_in = (const float*)d_in[0];
  const float* i_in = (const float*)d_in[1];
  const float* z_in = (const float*)d_in[2];
  const float* o_in = (const float*)d_in[3];
  const float* c0   = (const float*)d_in[4];
  const float* h0   = (const float*)d_in[5];
  const float* W_Fx = (const float*)d_in[6];  const float* b_Fx = (const float*)d_in[7];
  const float* W_Ix = (const float*)d_in[8];  const float* b_Ix = (const float*)d_in[9];
  const float* W_Zx = (const float*)d_in[10]; const float* b_Zx = (const float*)d_in[11];
  const float* W_Ox = (const float*)d_in[12]; const float* b_Ox = (const float*)d_in[13];
  const float* W_Fh = (const float*)d_in[14]; const float* b_Fh = (const float*)d_in[15];
  const float* W_Ih = (const float*)d_in[16]; const float* b_Ih = (const float*)d_in[17];
  const float* W_Zh = (const float*)d_in[18]; const float* b_Zh = (const float*)d_in[19];
  const float* W_Oh = (const float*)d_in[20]; const float* b_Oh = (const float*)d_in[21];
  const float* W_post = (const float*)d_in[22]; const float* b_post = (const float*)d_in[23];

  char* ws = (char*)d_ws;
  unsigned short* xg    = (unsigned short*)(ws);
  unsigned short* hs    = (unsigned short*)(ws + XG_BYTES);
  unsigned short* wt    = (unsigned short*)(ws + WT_OFF);

  float* y  = (float*)d_out;
  float* oc = y + 16777216;   // 16*1024*1024
  float* oh = oc + 16384;

  k_prep<<<dim3(16,16,9), 256, 0, stream>>>(W_Fx, W_Ix, W_Zx, W_Ox, W_post,
                                            W_Fh, W_Ih, W_Zh, W_Oh, wt);
  k_init<<<64, 256, 0, stream>>>(h0, hs);
  k_fill<<<8192, 256, 0, stream>>>((unsigned*)hs);
  k_xproj<<<dim3(128,8,4), 256, 0, stream>>>(f_in, i_in, z_in, o_in,
                                             b_Fx, b_Ix, b_Zx, b_Ox, wt, xg);
  k_recur<<<64, 256, 0, stream>>>(wt + (size_t)5*1024*1024,
                                  b_Fh, b_Ih, b_Zh, b_Oh,
                                  c0, xg, hs, oc, oh);
  k_post<<<dim3(128,8), 256, 0, stream>>>(hs, wt, b_post, y);
}